// Round 2
// baseline (1214.629 us; speedup 1.0000x reference)
//
#include <hip/hip_runtime.h>
#include <math.h>

// Problem constants (from reference)
#define NROWS 18432
#define IN_DIM 1024
#define HID_DIM 4096
#define OUT_DIM 4096

typedef __attribute__((ext_vector_type(8))) short bf16x8;
typedef __attribute__((ext_vector_type(4))) float f32x4;

typedef const __attribute__((address_space(1))) char gchar;
typedef __attribute__((address_space(3))) char lchar;

__device__ __forceinline__ unsigned short f2bf(float f) {
    union { float f; unsigned u; } v; v.f = f;
    unsigned r = v.u + 0x7fffu + ((v.u >> 16) & 1u);  // RNE
    return (unsigned short)(r >> 16);
}

// ---------------- conversion kernels ----------------

// 8 floats -> 8 bf16 per thread
__global__ void cvt_f32_bf16_k(const float4* __restrict__ in, uint4* __restrict__ out, int nvec) {
    int i = blockIdx.x * blockDim.x + threadIdx.x;
    if (i >= nvec) return;
    float4 a = in[2 * i], b = in[2 * i + 1];
    union { unsigned short s[8]; uint4 v; } o;
    o.s[0] = f2bf(a.x); o.s[1] = f2bf(a.y); o.s[2] = f2bf(a.z); o.s[3] = f2bf(a.w);
    o.s[4] = f2bf(b.x); o.s[5] = f2bf(b.y); o.s[6] = f2bf(b.z); o.s[7] = f2bf(b.w);
    out[i] = o.v;
}

// 8 int32 (quantized int8 values, sign-extended to int32 by the harness) -> 8 bf16.
// Values in [-127,127] are EXACT in bf16.
__global__ void cvt_i32_bf16_k(const int4* __restrict__ in, uint4* __restrict__ out, int nvec) {
    int i = blockIdx.x * blockDim.x + threadIdx.x;
    if (i >= nvec) return;
    int4 a = in[2 * i], b = in[2 * i + 1];
    union { unsigned short s[8]; uint4 v; } o;
    o.s[0] = f2bf((float)a.x); o.s[1] = f2bf((float)a.y);
    o.s[2] = f2bf((float)a.z); o.s[3] = f2bf((float)a.w);
    o.s[4] = f2bf((float)b.x); o.s[5] = f2bf((float)b.y);
    o.s[6] = f2bf((float)b.z); o.s[7] = f2bf((float)b.w);
    out[i] = o.v;
}

// ---------------- GEMM: C[M][Nn] = A[M][K] * B[Nn][K]^T, epilogue scale/bias (+gelu) ----------------
// EPI==0: h = gelu(acc*scale+bias) -> bf16 ; EPI==1: out = acc*scale+bias -> f32
// 128x128 block tile, 4 waves (2x2), 64x64 per wave, BK=64, mfma 16x16x32 bf16.
template<int EPI>
__global__ __launch_bounds__(256)
void gemm_bt(const unsigned short* __restrict__ A, const unsigned short* __restrict__ B,
             const float* __restrict__ scale, const float* __restrict__ bias,
             void* __restrict__ Cout, int Nn, int K) {
    __shared__ __align__(16) unsigned short lsA[128 * 64];
    __shared__ __align__(16) unsigned short lsB[128 * 64];

    const int tid  = threadIdx.x;
    const int lane = tid & 63;
    const int wid  = tid >> 6;
    const int wm = wid >> 1, wn = wid & 1;
    const int tm = blockIdx.y, tn = blockIdx.x;

    f32x4 acc[4][4] = {};

    const size_t rowbytes = (size_t)K * 2;
    const char* Ab = (const char*)A + (size_t)tm * 128 * rowbytes;
    const char* Bb = (const char*)B + (size_t)tn * 128 * rowbytes;

    // staging geometry: tile = 128 rows x 128 bytes (64 bf16); 1024 chunks of 16B; 4 per thread
    size_t goff[4];
    int    loff[4];
    #pragma unroll
    for (int p = 0; p < 4; ++p) {
        int q   = tid + p * 256;
        int row = q >> 3;
        int cb  = (q & 7) * 16;
        goff[p] = (size_t)row * rowbytes + (size_t)cb;
        loff[p] = q * 16;
    }

    const int lrow = lane & 15;
    const int lk   = (lane >> 4) * 8;

    for (int kt = 0; kt < K; kt += 64) {
        #pragma unroll
        for (int p = 0; p < 4; ++p) {
            __builtin_amdgcn_global_load_lds((gchar*)(Ab + goff[p] + (size_t)kt * 2),
                                             (lchar*)((char*)lsA + loff[p]), 16, 0, 0);
            __builtin_amdgcn_global_load_lds((gchar*)(Bb + goff[p] + (size_t)kt * 2),
                                             (lchar*)((char*)lsB + loff[p]), 16, 0, 0);
        }
        __syncthreads();   // compiler emits vmcnt(0) drain before barrier
        #pragma unroll
        for (int kk = 0; kk < 2; ++kk) {
            bf16x8 af[4], bfr[4];
            #pragma unroll
            for (int i = 0; i < 4; ++i) {
                af[i]  = *(const bf16x8*)&lsA[(wm * 64 + i * 16 + lrow) * 64 + kk * 32 + lk];
                bfr[i] = *(const bf16x8*)&lsB[(wn * 64 + i * 16 + lrow) * 64 + kk * 32 + lk];
            }
            #pragma unroll
            for (int i = 0; i < 4; ++i)
                #pragma unroll
                for (int j = 0; j < 4; ++j)
                    acc[i][j] = __builtin_amdgcn_mfma_f32_16x16x32_bf16(af[i], bfr[j], acc[i][j], 0, 0, 0);
        }
        __syncthreads();
    }

    // epilogue: C/D layout col=lane&15, row=(lane>>4)*4+r  [guide m89/m91]
    const int m0 = tm * 128 + wm * 64;
    const int n0 = tn * 128 + wn * 64;
    #pragma unroll
    for (int j = 0; j < 4; ++j) {
        int col = n0 + j * 16 + lrow;
        float sc = scale[col];
        float bi = bias[col];
        #pragma unroll
        for (int i = 0; i < 4; ++i) {
            int r0 = m0 + i * 16 + (lane >> 4) * 4;
            #pragma unroll
            for (int r = 0; r < 4; ++r) {
                float v = acc[i][j][r] * sc + bi;
                if (EPI == 0) {
                    float g = 0.5f * v * (1.0f + erff(v * 0.70710678118654752f));
                    ((unsigned short*)Cout)[(size_t)(r0 + r) * Nn + col] = f2bf(g);
                } else {
                    ((float*)Cout)[(size_t)(r0 + r) * Nn + col] = v;
                }
            }
        }
    }
}

extern "C" void kernel_launch(void* const* d_in, const int* in_sizes, int n_in,
                              void* d_out, int out_size, void* d_ws, size_t ws_size,
                              hipStream_t stream) {
    const float* x   = (const float*)d_in[0];
    const int*   w1q = (const int*)d_in[1];    // int8 values, harness-materialized as int32
    const float* s1  = (const float*)d_in[2];
    const float* b1  = (const float*)d_in[3];
    const int*   w2q = (const int*)d_in[4];    // int8 values, harness-materialized as int32
    const float* s2  = (const float*)d_in[5];
    const float* b2  = (const float*)d_in[6];
    float*       out = (float*)d_out;

    char* ws = (char*)d_ws;
    const size_t XBF  = (size_t)NROWS   * IN_DIM  * 2;  // 37.75 MB
    const size_t W1BF = (size_t)HID_DIM * IN_DIM  * 2;  //  8.39 MB
    const size_t W2BF = (size_t)OUT_DIM * HID_DIM * 2;  // 33.55 MB
    const size_t FIXED = XBF + W1BF + W2BF;

    unsigned short* xbf  = (unsigned short*)ws;
    unsigned short* w1bf = (unsigned short*)(ws + XBF);
    unsigned short* w2bf = (unsigned short*)(ws + XBF + W1BF);
    unsigned short* hbuf = (unsigned short*)(ws + FIXED);

    // conversions (weights exact in bf16; scales applied in GEMM epilogue)
    {
        int nvx = NROWS * IN_DIM / 8;
        cvt_f32_bf16_k<<<(nvx + 255) / 256, 256, 0, stream>>>((const float4*)x, (uint4*)xbf, nvx);
        int nv1 = HID_DIM * IN_DIM / 8;
        cvt_i32_bf16_k<<<(nv1 + 255) / 256, 256, 0, stream>>>((const int4*)w1q, (uint4*)w1bf, nv1);
        int nv2 = OUT_DIM * HID_DIM / 8;
        cvt_i32_bf16_k<<<(nv2 + 255) / 256, 256, 0, stream>>>((const int4*)w2q, (uint4*)w2bf, nv2);
    }

    // chunk M so h (chunk_rows x HID bf16) fits in remaining workspace
    size_t avail = (ws_size > FIXED) ? (ws_size - FIXED) : 0;
    long rp = (long)(avail / ((size_t)HID_DIM * 2));
    rp = (rp / 128) * 128;
    if (rp > NROWS) rp = NROWS;
    if (rp < 128)   rp = 128;  // minimal chunk; requires ws_size >= ~81 MB

    for (int r0 = 0; r0 < NROWS; r0 += (int)rp) {
        int rows = (int)(((long)(NROWS - r0) < rp) ? (NROWS - r0) : rp);
        dim3 g1(HID_DIM / 128, rows / 128);
        gemm_bt<0><<<g1, 256, 0, stream>>>(xbf + (size_t)r0 * IN_DIM, w1bf, s1, b1,
                                           (void*)hbuf, HID_DIM, IN_DIM);
        dim3 g2(OUT_DIM / 128, rows / 128);
        gemm_bt<1><<<g2, 256, 0, stream>>>(hbuf, w2bf, s2, b2,
                                           (void*)(out + (size_t)r0 * OUT_DIM), OUT_DIM, HID_DIM);
    }
    (void)in_sizes; (void)n_in; (void)out_size;
}

// Round 4
// 856.914 us; speedup vs baseline: 1.4174x; 1.4174x over previous
//
#include <hip/hip_runtime.h>
#include <math.h>

// Problem constants (from reference)
#define NROWS 18432
#define IN_DIM 1024
#define HID_DIM 4096
#define OUT_DIM 4096
#define NTN 16   // 4096/256 column tiles (both layers)

typedef __attribute__((ext_vector_type(8))) short bf16x8;
typedef __attribute__((ext_vector_type(4))) float f32x4;

typedef const __attribute__((address_space(1))) char gchar;
typedef __attribute__((address_space(3))) char lchar;

__device__ __forceinline__ unsigned short f2bf(float f) {
    union { float f; unsigned u; } v; v.f = f;
    unsigned r = v.u + 0x7fffu + ((v.u >> 16) & 1u);  // RNE
    return (unsigned short)(r >> 16);
}

__device__ __forceinline__ f32x4 MFMA16(bf16x8 a, bf16x8 b, f32x4 c) {
    return __builtin_amdgcn_mfma_f32_16x16x32_bf16(a, b, c, 0, 0, 0);
}

// ---------------- conversion kernels ----------------

__global__ void cvt_f32_bf16_k(const float4* __restrict__ in, uint4* __restrict__ out, int nvec) {
    int i = blockIdx.x * blockDim.x + threadIdx.x;
    if (i >= nvec) return;
    float4 a = in[2 * i], b = in[2 * i + 1];
    union { unsigned short s[8]; uint4 v; } o;
    o.s[0] = f2bf(a.x); o.s[1] = f2bf(a.y); o.s[2] = f2bf(a.z); o.s[3] = f2bf(a.w);
    o.s[4] = f2bf(b.x); o.s[5] = f2bf(b.y); o.s[6] = f2bf(b.z); o.s[7] = f2bf(b.w);
    out[i] = o.v;
}

// int8 values harness-materialized as int32; exact in bf16
__global__ void cvt_i32_bf16_k(const int4* __restrict__ in, uint4* __restrict__ out, int nvec) {
    int i = blockIdx.x * blockDim.x + threadIdx.x;
    if (i >= nvec) return;
    int4 a = in[2 * i], b = in[2 * i + 1];
    union { unsigned short s[8]; uint4 v; } o;
    o.s[0] = f2bf((float)a.x); o.s[1] = f2bf((float)a.y);
    o.s[2] = f2bf((float)a.z); o.s[3] = f2bf((float)a.w);
    o.s[4] = f2bf((float)b.x); o.s[5] = f2bf((float)b.y);
    o.s[6] = f2bf((float)b.z); o.s[7] = f2bf((float)b.w);
    out[i] = o.v;
}

// ---------------- 256x256 8-phase GEMM: C = A[M][K] * B[256-col tile][K]^T ----------------
// 8 waves (2M x 4N), per-wave 128x64 out (interleaved blocks), BK=64, double-buffered 128KB LDS.
// T2 XOR swizzle on LDS, T4 counted vmcnt(4) (tail iteration drains vmcnt(0) -- ledger fix),
// T5 setprio, T1 XCD swizzle.
// EPI==0: bf16 gelu(acc*sc+bi); EPI==1: f32 acc*sc+bi. Output row-stride hardcoded 4096.
template<int EPI>
__global__ __launch_bounds__(512, 2)
void gemm8p(const unsigned short* __restrict__ A, const unsigned short* __restrict__ B,
            const float* __restrict__ scale, const float* __restrict__ bias,
            void* __restrict__ Cout, int K) {
    extern __shared__ __align__(16) char sm[];   // 131072 bytes dynamic

    const int tid  = threadIdx.x;
    const int lane = tid & 63;
    const int wid  = tid >> 6;
    const int wm   = wid >> 2, wn = wid & 3;
    const int widb = wid << 10;

    // T1: bijective XCD swizzle (m204)
    const int nwg  = gridDim.x;
    const int q    = nwg >> 3, r = nwg & 7;
    const int xcd  = blockIdx.x & 7, bidx = blockIdx.x >> 3;
    const int swz  = xcd * q + (xcd < r ? xcd : r) + bidx;
    const int tm   = swz / NTN, tn = swz % NTN;

    const size_t rowbytes = (size_t)K * 2;
    const char* Ag = (const char*)A + (size_t)tm * 256 * rowbytes;
    const char* Bg = (const char*)B + (size_t)tn * 256 * rowbytes;

    const int l16   = lane & 15;
    const int colk0 = (((lane >> 4) ^ (lane & 7)) << 4);       // swizzled col for kk=0
    const int colk1 = (((4 | (lane >> 4)) ^ (lane & 7)) << 4); // swizzled col for kk=1

    f32x4  acc[8][4] = {};
    bf16x8 af[4][2], bl[2][2], bh[2][2];

    const int NT = K >> 6;

// stage one 16KB quarter (PART: 0=rows 0-127, 1=rows 128-255) of a 256x64bf16 tile.
// LDS dest linear (wave-uniform base + lane*16); global source pre-inverse-swizzled (rule 21).
#define STAGE(GB, LB, PART, KTB) { \
    _Pragma("unroll") \
    for (int l_ = 0; l_ < 2; ++l_) { \
        const int po_   = ((PART) << 14) + (l_ << 13) + widb + (lane << 4); \
        const int prow_ = po_ >> 7; \
        const int lcb_  = (po_ & 127) ^ ((prow_ & 7) << 4); \
        __builtin_amdgcn_global_load_lds( \
            (gchar*)((GB) + (size_t)prow_ * rowbytes + (KTB) + (size_t)lcb_), \
            (lchar*)((LB) + po_), 16, 0, 0); \
    } }

#define WAITV4 asm volatile("s_waitcnt vmcnt(4)" ::: "memory")
#define WAITV0 asm volatile("s_waitcnt vmcnt(0)" ::: "memory")
#define BARR   { asm volatile("" ::: "memory"); __builtin_amdgcn_s_barrier(); asm volatile("" ::: "memory"); }

    // prologue: tile 0 -> buffer 0; issue order matches consumption priority
    STAGE(Ag, sm,         0, (size_t)0);   // A-lo
    STAGE(Bg, sm + 32768, 0, (size_t)0);   // B-lo
    STAGE(Bg, sm + 32768, 1, (size_t)0);   // B-hi
    STAGE(Ag, sm,         1, (size_t)0);   // A-hi
    WAITV4; BARR;                          // A-lo,B-lo landed; B-hi,A-hi may fly

    for (int t = 0; t < NT; ++t) {
        char* Al = sm + ((t & 1) << 16);
        char* Bl = Al + 32768;
        char* An = sm + (((t & 1) ^ 1) << 16);
        char* Bn = An + 32768;
        const bool   pf  = (t + 1 < NT);
        const size_t ktb = ((size_t)(t + 1)) << 7;  // (t+1)*64 bf16 = *128 bytes

        // ---- phase 0: read A-lo + B-lo frags; stage A-lo(t+1) ----
        {
            const int ab = (wm << 6) + l16;
            #pragma unroll
            for (int mm = 0; mm < 4; ++mm) {
                const int ro = (ab + mm * 16) * 128;
                af[mm][0] = *(const bf16x8*)(Al + ro + colk0);
                af[mm][1] = *(const bf16x8*)(Al + ro + colk1);
            }
            const int bb = (wn << 5) + l16;
            #pragma unroll
            for (int nn = 0; nn < 2; ++nn) {
                const int ro = (bb + nn * 16) * 128;
                bl[nn][0] = *(const bf16x8*)(Bl + ro + colk0);
                bl[nn][1] = *(const bf16x8*)(Bl + ro + colk1);
            }
            if (pf) { STAGE(Ag, An, 0, ktb); WAITV4; }
            else    { WAITV0; }           // tail: nothing staged, counted wait would no-op -> drain
            BARR;                          // guarantees B-hi(t) for phase 1
            __builtin_amdgcn_s_setprio(1);
            #pragma unroll
            for (int mm = 0; mm < 4; ++mm)
                #pragma unroll
                for (int nn = 0; nn < 2; ++nn) {
                    acc[mm][nn] = MFMA16(af[mm][0], bl[nn][0], acc[mm][nn]);
                    acc[mm][nn] = MFMA16(af[mm][1], bl[nn][1], acc[mm][nn]);
                }
            __builtin_amdgcn_s_setprio(0);
            BARR;
        }
        // ---- phase 1: read B-hi frags; stage B-lo(t+1) ----
        {
            const int bb = 128 + (wn << 5) + l16;
            #pragma unroll
            for (int nn = 0; nn < 2; ++nn) {
                const int ro = (bb + nn * 16) * 128;
                bh[nn][0] = *(const bf16x8*)(Bl + ro + colk0);
                bh[nn][1] = *(const bf16x8*)(Bl + ro + colk1);
            }
            if (pf) { STAGE(Bg, Bn, 0, ktb); WAITV4; }  // tail: all landed, no wait
            BARR;                          // guarantees A-hi(t) for phase 2
            __builtin_amdgcn_s_setprio(1);
            #pragma unroll
            for (int mm = 0; mm < 4; ++mm)
                #pragma unroll
                for (int nn = 0; nn < 2; ++nn) {
                    acc[mm][2 + nn] = MFMA16(af[mm][0], bh[nn][0], acc[mm][2 + nn]);
                    acc[mm][2 + nn] = MFMA16(af[mm][1], bh[nn][1], acc[mm][2 + nn]);
                }
            __builtin_amdgcn_s_setprio(0);
            BARR;
        }
        // ---- phase 2: read A-hi frags; stage B-hi(t+1) ----
        {
            const int ab = 128 + (wm << 6) + l16;
            #pragma unroll
            for (int mm = 0; mm < 4; ++mm) {
                const int ro = (ab + mm * 16) * 128;
                af[mm][0] = *(const bf16x8*)(Al + ro + colk0);
                af[mm][1] = *(const bf16x8*)(Al + ro + colk1);
            }
            if (pf) STAGE(Bg, Bn, 1, ktb);
            BARR;                          // phase 3 reads nothing new: no vmcnt
            __builtin_amdgcn_s_setprio(1);
            #pragma unroll
            for (int mm = 0; mm < 4; ++mm)
                #pragma unroll
                for (int nn = 0; nn < 2; ++nn) {
                    acc[4 + mm][nn] = MFMA16(af[mm][0], bl[nn][0], acc[4 + mm][nn]);
                    acc[4 + mm][nn] = MFMA16(af[mm][1], bl[nn][1], acc[4 + mm][nn]);
                }
            __builtin_amdgcn_s_setprio(0);
            BARR;
        }
        // ---- phase 3: stage A-hi(t+1) ----
        {
            if (pf) { STAGE(Ag, An, 1, ktb); WAITV4; }  // guarantees A-lo,B-lo(t+1) for next phase 0
            BARR;
            __builtin_amdgcn_s_setprio(1);
            #pragma unroll
            for (int mm = 0; mm < 4; ++mm)
                #pragma unroll
                for (int nn = 0; nn < 2; ++nn) {
                    acc[4 + mm][2 + nn] = MFMA16(af[mm][0], bh[nn][0], acc[4 + mm][2 + nn]);
                    acc[4 + mm][2 + nn] = MFMA16(af[mm][1], bh[nn][1], acc[4 + mm][2 + nn]);
                }
            __builtin_amdgcn_s_setprio(0);
            BARR;
        }
    }
#undef STAGE
#undef WAITV4
#undef WAITV0
#undef BARR

    // epilogue: C/D frag layout col=lane&15, row=(lane>>4)*4+r  [m89/m91]
    const int rg = (lane >> 4) << 2;
    #pragma unroll
    for (int j = 0; j < 4; ++j) {
        const int col = tn * 256 + ((j >> 1) << 7) + (wn << 5) + ((j & 1) << 4) + l16;
        const float sc = scale[col];
        const float bi = bias[col];
        #pragma unroll
        for (int m = 0; m < 8; ++m) {
            const int row0 = tm * 256 + ((m >> 2) << 7) + (wm << 6) + ((m & 3) << 4) + rg;
            #pragma unroll
            for (int rr = 0; rr < 4; ++rr) {
                float v = acc[m][j][rr] * sc + bi;
                if (EPI == 0) {
                    float g = 0.5f * v * (1.0f + erff(v * 0.70710678118654752f));
                    ((unsigned short*)Cout)[(size_t)(row0 + rr) * 4096 + col] = f2bf(g);
                } else {
                    ((float*)Cout)[(size_t)(row0 + rr) * 4096 + col] = v;
                }
            }
        }
    }
}

extern "C" void kernel_launch(void* const* d_in, const int* in_sizes, int n_in,
                              void* d_out, int out_size, void* d_ws, size_t ws_size,
                              hipStream_t stream) {
    const float* x   = (const float*)d_in[0];
    const int*   w1q = (const int*)d_in[1];
    const float* s1  = (const float*)d_in[2];
    const float* b1  = (const float*)d_in[3];
    const int*   w2q = (const int*)d_in[4];
    const float* s2  = (const float*)d_in[5];
    const float* b2  = (const float*)d_in[6];
    float*       out = (float*)d_out;

    // allow 128 KiB dynamic LDS (idempotent, not a stream op)
    hipFuncSetAttribute((const void*)gemm8p<0>, hipFuncAttributeMaxDynamicSharedMemorySize, 131072);
    hipFuncSetAttribute((const void*)gemm8p<1>, hipFuncAttributeMaxDynamicSharedMemorySize, 131072);

    char* ws = (char*)d_ws;
    const size_t XBF  = (size_t)NROWS   * IN_DIM  * 2;
    const size_t W1BF = (size_t)HID_DIM * IN_DIM  * 2;
    const size_t W2BF = (size_t)OUT_DIM * HID_DIM * 2;
    const size_t FIXED = XBF + W1BF + W2BF;

    unsigned short* xbf  = (unsigned short*)ws;
    unsigned short* w1bf = (unsigned short*)(ws + XBF);
    unsigned short* w2bf = (unsigned short*)(ws + XBF + W1BF);
    unsigned short* hbuf = (unsigned short*)(ws + FIXED);

    {
        int nvx = NROWS * IN_DIM / 8;
        cvt_f32_bf16_k<<<(nvx + 255) / 256, 256, 0, stream>>>((const float4*)x, (uint4*)xbf, nvx);
        int nv1 = HID_DIM * IN_DIM / 8;
        cvt_i32_bf16_k<<<(nv1 + 255) / 256, 256, 0, stream>>>((const int4*)w1q, (uint4*)w1bf, nv1);
        int nv2 = OUT_DIM * HID_DIM / 8;
        cvt_i32_bf16_k<<<(nv2 + 255) / 256, 256, 0, stream>>>((const int4*)w2q, (uint4*)w2bf, nv2);
    }

    // chunk M (multiples of 256) so h fits in remaining workspace
    size_t avail = (ws_size > FIXED) ? (ws_size - FIXED) : 0;
    long rp = (long)(avail / ((size_t)HID_DIM * 2));
    rp = (rp / 256) * 256;
    if (rp > NROWS) rp = NROWS;
    if (rp < 256)   rp = 256;

    for (int r0 = 0; r0 < NROWS; r0 += (int)rp) {
        int rows = (int)(((long)(NROWS - r0) < rp) ? (NROWS - r0) : rp);
        dim3 g(NTN * (rows / 256));
        gemm8p<0><<<g, 512, 131072, stream>>>(xbf + (size_t)r0 * IN_DIM, w1bf, s1, b1,
                                              (void*)hbuf, IN_DIM);
        gemm8p<1><<<g, 512, 131072, stream>>>(hbuf, w2bf, s2, b2,
                                              (void*)(out + (size_t)r0 * OUT_DIM), HID_DIM);
    }
    (void)in_sizes; (void)n_in; (void)out_size;
}

// Round 5
// 854.977 us; speedup vs baseline: 1.4207x; 1.0023x over previous
//
#include <hip/hip_runtime.h>
#include <math.h>

// Problem constants (from reference)
#define NROWS 18432
#define IN_DIM 1024
#define HID_DIM 4096
#define OUT_DIM 4096
#define NTN 16   // 4096/256 column tiles (both layers)

typedef __attribute__((ext_vector_type(8))) short bf16x8;
typedef __attribute__((ext_vector_type(4))) float f32x4;

typedef const __attribute__((address_space(1))) char gchar;
typedef __attribute__((address_space(3))) char lchar;

__device__ __forceinline__ unsigned short f2bf(float f) {
    union { float f; unsigned u; } v; v.f = f;
    unsigned r = v.u + 0x7fffu + ((v.u >> 16) & 1u);  // RNE
    return (unsigned short)(r >> 16);
}

__device__ __forceinline__ f32x4 MFMA16(bf16x8 a, bf16x8 b, f32x4 c) {
    return __builtin_amdgcn_mfma_f32_16x16x32_bf16(a, b, c, 0, 0, 0);
}

// ---------------- conversion kernels ----------------

__global__ void cvt_f32_bf16_k(const float4* __restrict__ in, uint4* __restrict__ out, int nvec) {
    int i = blockIdx.x * blockDim.x + threadIdx.x;
    if (i >= nvec) return;
    float4 a = in[2 * i], b = in[2 * i + 1];
    union { unsigned short s[8]; uint4 v; } o;
    o.s[0] = f2bf(a.x); o.s[1] = f2bf(a.y); o.s[2] = f2bf(a.z); o.s[3] = f2bf(a.w);
    o.s[4] = f2bf(b.x); o.s[5] = f2bf(b.y); o.s[6] = f2bf(b.z); o.s[7] = f2bf(b.w);
    out[i] = o.v;
}

// int8 values harness-materialized as int32; exact in bf16
__global__ void cvt_i32_bf16_k(const int4* __restrict__ in, uint4* __restrict__ out, int nvec) {
    int i = blockIdx.x * blockDim.x + threadIdx.x;
    if (i >= nvec) return;
    int4 a = in[2 * i], b = in[2 * i + 1];
    union { unsigned short s[8]; uint4 v; } o;
    o.s[0] = f2bf((float)a.x); o.s[1] = f2bf((float)a.y);
    o.s[2] = f2bf((float)a.z); o.s[3] = f2bf((float)a.w);
    o.s[4] = f2bf((float)b.x); o.s[5] = f2bf((float)b.y);
    o.s[6] = f2bf((float)b.z); o.s[7] = f2bf((float)b.w);
    out[i] = o.v;
}

// ---------------- 256x256 8-phase GEMM: C = A[M][K] * B[256-col tile][K]^T ----------------
// 8 waves (2M x 4N), per-wave 128x64 out (interleaved blocks), BK=64, double-buffered 128KB LDS.
// T2 XOR swizzle on LDS, T4 counted vmcnt (clobber-FREE asm + sched_barrier pins -- a "memory"
// clobber makes SIInsertWaitcnts emit vmcnt(0) before the asm, silently draining the pipeline),
// T5 setprio, T1 XCD swizzle. Tail iteration drains vmcnt(0) (ledger fix, round 3).
// EPI==0: bf16 gelu(acc*sc+bi); EPI==1: f32 acc*sc+bi. Output row-stride hardcoded 4096.
template<int EPI>
__global__ __launch_bounds__(512, 2)
void gemm8p(const unsigned short* __restrict__ A, const unsigned short* __restrict__ B,
            const float* __restrict__ scale, const float* __restrict__ bias,
            void* __restrict__ Cout, int K) {
    extern __shared__ __align__(16) char sm[];   // 131072 bytes dynamic

    const int tid  = threadIdx.x;
    const int lane = tid & 63;
    const int wid  = tid >> 6;
    const int wm   = wid >> 2, wn = wid & 3;
    const int widb = wid << 10;

    // T1: bijective XCD swizzle (m204)
    const int nwg  = gridDim.x;
    const int q    = nwg >> 3, r = nwg & 7;
    const int xcd  = blockIdx.x & 7, bidx = blockIdx.x >> 3;
    const int swz  = xcd * q + (xcd < r ? xcd : r) + bidx;
    const int tm   = swz / NTN, tn = swz % NTN;

    const size_t rowbytes = (size_t)K * 2;
    const char* Ag = (const char*)A + (size_t)tm * 256 * rowbytes;
    const char* Bg = (const char*)B + (size_t)tn * 256 * rowbytes;

    const int l16   = lane & 15;
    const int colk0 = (((lane >> 4) ^ (lane & 7)) << 4);       // swizzled col for kk=0
    const int colk1 = (((4 | (lane >> 4)) ^ (lane & 7)) << 4); // swizzled col for kk=1

    f32x4  acc[8][4] = {};
    bf16x8 af[4][2], bl[2][2], bh[2][2];

    const int NT = K >> 6;

// stage one 16KB quarter (PART: 0=rows 0-127, 1=rows 128-255) of a 256x64bf16 tile.
// LDS dest linear (wave-uniform base + lane*16); global source pre-inverse-swizzled (rule 21).
#define STAGE(GB, LB, PART, KTB) { \
    _Pragma("unroll") \
    for (int l_ = 0; l_ < 2; ++l_) { \
        const int po_   = ((PART) << 14) + (l_ << 13) + widb + (lane << 4); \
        const int prow_ = po_ >> 7; \
        const int lcb_  = (po_ & 127) ^ ((prow_ & 7) << 4); \
        __builtin_amdgcn_global_load_lds( \
            (gchar*)((GB) + (size_t)prow_ * rowbytes + (KTB) + (size_t)lcb_), \
            (lchar*)((LB) + po_), 16, 0, 0); \
    } }

#define SFENCE __builtin_amdgcn_sched_barrier(0)
#define WAITV4 { SFENCE; asm volatile("s_waitcnt vmcnt(4)"); SFENCE; }
#define WAITV0 { SFENCE; asm volatile("s_waitcnt vmcnt(0)"); SFENCE; }
#define BARR   { SFENCE; __builtin_amdgcn_s_barrier(); SFENCE; }

    // prologue: tile 0 -> buffer 0; issue order matches consumption priority
    STAGE(Ag, sm,         0, (size_t)0);   // A-lo
    STAGE(Bg, sm + 32768, 0, (size_t)0);   // B-lo
    STAGE(Bg, sm + 32768, 1, (size_t)0);   // B-hi
    STAGE(Ag, sm,         1, (size_t)0);   // A-hi
    WAITV4; BARR;                          // A-lo,B-lo landed; B-hi,A-hi may fly

    for (int t = 0; t < NT; ++t) {
        char* Al = sm + ((t & 1) << 16);
        char* Bl = Al + 32768;
        char* An = sm + (((t & 1) ^ 1) << 16);
        char* Bn = An + 32768;
        const bool   pf  = (t + 1 < NT);
        const size_t ktb = ((size_t)(t + 1)) << 7;  // (t+1)*64 bf16 = *128 bytes

        // ---- phase 0: read A-lo + B-lo frags; stage A-lo(t+1) ----
        {
            const int ab = (wm << 6) + l16;
            #pragma unroll
            for (int mm = 0; mm < 4; ++mm) {
                const int ro = (ab + mm * 16) * 128;
                af[mm][0] = *(const bf16x8*)(Al + ro + colk0);
                af[mm][1] = *(const bf16x8*)(Al + ro + colk1);
            }
            const int bb = (wn << 5) + l16;
            #pragma unroll
            for (int nn = 0; nn < 2; ++nn) {
                const int ro = (bb + nn * 16) * 128;
                bl[nn][0] = *(const bf16x8*)(Bl + ro + colk0);
                bl[nn][1] = *(const bf16x8*)(Bl + ro + colk1);
            }
            if (pf) { STAGE(Ag, An, 0, ktb); WAITV4; }
            else    { WAITV0; }           // tail: nothing staged, counted wait would no-op -> drain
            BARR;                          // guarantees B-hi(t) for phase 1
            __builtin_amdgcn_s_setprio(1);
            #pragma unroll
            for (int mm = 0; mm < 4; ++mm)
                #pragma unroll
                for (int nn = 0; nn < 2; ++nn) {
                    acc[mm][nn] = MFMA16(af[mm][0], bl[nn][0], acc[mm][nn]);
                    acc[mm][nn] = MFMA16(af[mm][1], bl[nn][1], acc[mm][nn]);
                }
            __builtin_amdgcn_s_setprio(0);
            BARR;
        }
        // ---- phase 1: read B-hi frags; stage B-lo(t+1) ----
        {
            const int bb = 128 + (wn << 5) + l16;
            #pragma unroll
            for (int nn = 0; nn < 2; ++nn) {
                const int ro = (bb + nn * 16) * 128;
                bh[nn][0] = *(const bf16x8*)(Bl + ro + colk0);
                bh[nn][1] = *(const bf16x8*)(Bl + ro + colk1);
            }
            if (pf) { STAGE(Bg, Bn, 0, ktb); WAITV4; }  // tail: all landed, no wait
            BARR;                          // guarantees A-hi(t) for phase 2
            __builtin_amdgcn_s_setprio(1);
            #pragma unroll
            for (int mm = 0; mm < 4; ++mm)
                #pragma unroll
                for (int nn = 0; nn < 2; ++nn) {
                    acc[mm][2 + nn] = MFMA16(af[mm][0], bh[nn][0], acc[mm][2 + nn]);
                    acc[mm][2 + nn] = MFMA16(af[mm][1], bh[nn][1], acc[mm][2 + nn]);
                }
            __builtin_amdgcn_s_setprio(0);
            BARR;
        }
        // ---- phase 2: read A-hi frags; stage B-hi(t+1) ----
        {
            const int ab = 128 + (wm << 6) + l16;
            #pragma unroll
            for (int mm = 0; mm < 4; ++mm) {
                const int ro = (ab + mm * 16) * 128;
                af[mm][0] = *(const bf16x8*)(Al + ro + colk0);
                af[mm][1] = *(const bf16x8*)(Al + ro + colk1);
            }
            if (pf) STAGE(Bg, Bn, 1, ktb);
            BARR;                          // phase 3 reads nothing new: no vmcnt
            __builtin_amdgcn_s_setprio(1);
            #pragma unroll
            for (int mm = 0; mm < 4; ++mm)
                #pragma unroll
                for (int nn = 0; nn < 2; ++nn) {
                    acc[4 + mm][nn] = MFMA16(af[mm][0], bl[nn][0], acc[4 + mm][nn]);
                    acc[4 + mm][nn] = MFMA16(af[mm][1], bl[nn][1], acc[4 + mm][nn]);
                }
            __builtin_amdgcn_s_setprio(0);
            BARR;
        }
        // ---- phase 3: stage A-hi(t+1) ----
        {
            if (pf) { STAGE(Ag, An, 1, ktb); WAITV4; }  // guarantees A-lo,B-lo(t+1) for next phase 0
            BARR;
            __builtin_amdgcn_s_setprio(1);
            #pragma unroll
            for (int mm = 0; mm < 4; ++mm)
                #pragma unroll
                for (int nn = 0; nn < 2; ++nn) {
                    acc[4 + mm][2 + nn] = MFMA16(af[mm][0], bh[nn][0], acc[4 + mm][2 + nn]);
                    acc[4 + mm][2 + nn] = MFMA16(af[mm][1], bh[nn][1], acc[4 + mm][2 + nn]);
                }
            __builtin_amdgcn_s_setprio(0);
            BARR;
        }
    }
#undef STAGE
#undef SFENCE
#undef WAITV4
#undef WAITV0
#undef BARR

    // epilogue: C/D frag layout col=lane&15, row=(lane>>4)*4+r  [m89/m91]
    const int rg = (lane >> 4) << 2;
    #pragma unroll
    for (int j = 0; j < 4; ++j) {
        const int col = tn * 256 + ((j >> 1) << 7) + (wn << 5) + ((j & 1) << 4) + l16;
        const float sc = scale[col];
        const float bi = bias[col];
        #pragma unroll
        for (int m = 0; m < 8; ++m) {
            const int row0 = tm * 256 + ((m >> 2) << 7) + (wm << 6) + ((m & 3) << 4) + rg;
            #pragma unroll
            for (int rr = 0; rr < 4; ++rr) {
                float v = acc[m][j][rr] * sc + bi;
                if (EPI == 0) {
                    float g = 0.5f * v * (1.0f + erff(v * 0.70710678118654752f));
                    ((unsigned short*)Cout)[(size_t)(row0 + rr) * 4096 + col] = f2bf(g);
                } else {
                    ((float*)Cout)[(size_t)(row0 + rr) * 4096 + col] = v;
                }
            }
        }
    }
}

extern "C" void kernel_launch(void* const* d_in, const int* in_sizes, int n_in,
                              void* d_out, int out_size, void* d_ws, size_t ws_size,
                              hipStream_t stream) {
    const float* x   = (const float*)d_in[0];
    const int*   w1q = (const int*)d_in[1];
    const float* s1  = (const float*)d_in[2];
    const float* b1  = (const float*)d_in[3];
    const int*   w2q = (const int*)d_in[4];
    const float* s2  = (const float*)d_in[5];
    const float* b2  = (const float*)d_in[6];
    float*       out = (float*)d_out;

    // allow 128 KiB dynamic LDS (idempotent, not a stream op)
    hipFuncSetAttribute((const void*)gemm8p<0>, hipFuncAttributeMaxDynamicSharedMemorySize, 131072);
    hipFuncSetAttribute((const void*)gemm8p<1>, hipFuncAttributeMaxDynamicSharedMemorySize, 131072);

    char* ws = (char*)d_ws;
    const size_t XBF  = (size_t)NROWS   * IN_DIM  * 2;
    const size_t W1BF = (size_t)HID_DIM * IN_DIM  * 2;
    const size_t W2BF = (size_t)OUT_DIM * HID_DIM * 2;
    const size_t FIXED = XBF + W1BF + W2BF;

    unsigned short* xbf  = (unsigned short*)ws;
    unsigned short* w1bf = (unsigned short*)(ws + XBF);
    unsigned short* w2bf = (unsigned short*)(ws + XBF + W1BF);
    unsigned short* hbuf = (unsigned short*)(ws + FIXED);

    {
        int nvx = NROWS * IN_DIM / 8;
        cvt_f32_bf16_k<<<(nvx + 255) / 256, 256, 0, stream>>>((const float4*)x, (uint4*)xbf, nvx);
        int nv1 = HID_DIM * IN_DIM / 8;
        cvt_i32_bf16_k<<<(nv1 + 255) / 256, 256, 0, stream>>>((const int4*)w1q, (uint4*)w1bf, nv1);
        int nv2 = OUT_DIM * HID_DIM / 8;
        cvt_i32_bf16_k<<<(nv2 + 255) / 256, 256, 0, stream>>>((const int4*)w2q, (uint4*)w2bf, nv2);
    }

    // chunk M (multiples of 256) so h fits in remaining workspace
    size_t avail = (ws_size > FIXED) ? (ws_size - FIXED) : 0;
    long rp = (long)(avail / ((size_t)HID_DIM * 2));
    rp = (rp / 256) * 256;
    if (rp > NROWS) rp = NROWS;
    if (rp < 256)   rp = 256;

    for (int r0 = 0; r0 < NROWS; r0 += (int)rp) {
        int rows = (int)(((long)(NROWS - r0) < rp) ? (NROWS - r0) : rp);
        dim3 g(NTN * (rows / 256));
        gemm8p<0><<<g, 512, 131072, stream>>>(xbf + (size_t)r0 * IN_DIM, w1bf, s1, b1,
                                              (void*)hbuf, IN_DIM);
        gemm8p<1><<<g, 512, 131072, stream>>>(hbuf, w2bf, s2, b2,
                                              (void*)(out + (size_t)r0 * OUT_DIM), HID_DIM);
    }
    (void)in_sizes; (void)n_in; (void)out_size;
}

// Round 6
// 824.670 us; speedup vs baseline: 1.4729x; 1.0368x over previous
//
#include <hip/hip_runtime.h>
#include <math.h>

// Problem constants (from reference)
#define NROWS 18432
#define IN_DIM 1024
#define HID_DIM 4096
#define OUT_DIM 4096
#define NTN 16   // 4096/256 column tiles (both layers)

typedef __attribute__((ext_vector_type(8))) short bf16x8;
typedef __attribute__((ext_vector_type(4))) float f32x4;

typedef const __attribute__((address_space(1))) char gchar;
typedef __attribute__((address_space(3))) char lchar;

__device__ __forceinline__ unsigned short f2bf(float f) {
    union { float f; unsigned u; } v; v.f = f;
    unsigned r = v.u + 0x7fffu + ((v.u >> 16) & 1u);  // RNE
    return (unsigned short)(r >> 16);
}

__device__ __forceinline__ f32x4 MFMA16(bf16x8 a, bf16x8 b, f32x4 c) {
    return __builtin_amdgcn_mfma_f32_16x16x32_bf16(a, b, c, 0, 0, 0);
}

// ---------------- conversion kernels ----------------

__global__ void cvt_f32_bf16_k(const float4* __restrict__ in, uint4* __restrict__ out, int nvec) {
    int i = blockIdx.x * blockDim.x + threadIdx.x;
    if (i >= nvec) return;
    float4 a = in[2 * i], b = in[2 * i + 1];
    union { unsigned short s[8]; uint4 v; } o;
    o.s[0] = f2bf(a.x); o.s[1] = f2bf(a.y); o.s[2] = f2bf(a.z); o.s[3] = f2bf(a.w);
    o.s[4] = f2bf(b.x); o.s[5] = f2bf(b.y); o.s[6] = f2bf(b.z); o.s[7] = f2bf(b.w);
    out[i] = o.v;
}

// int8 values harness-materialized as int32; exact in bf16
__global__ void cvt_i32_bf16_k(const int4* __restrict__ in, uint4* __restrict__ out, int nvec) {
    int i = blockIdx.x * blockDim.x + threadIdx.x;
    if (i >= nvec) return;
    int4 a = in[2 * i], b = in[2 * i + 1];
    union { unsigned short s[8]; uint4 v; } o;
    o.s[0] = f2bf((float)a.x); o.s[1] = f2bf((float)a.y);
    o.s[2] = f2bf((float)a.z); o.s[3] = f2bf((float)a.w);
    o.s[4] = f2bf((float)b.x); o.s[5] = f2bf((float)b.y);
    o.s[6] = f2bf((float)b.z); o.s[7] = f2bf((float)b.w);
    out[i] = o.v;
}

// ---------------- 256x256 8-phase GEMM: C = A[M][K] * B[256-col tile][K]^T ----------------
// 8 waves (2M x 4N), per-wave 128x64 out (interleaved blocks), BK=64, double-buffered 128KB LDS.
// T2 XOR swizzle, T4 counted vmcnt, T5 setprio, T1 XCD swizzle.
// ONE barrier per phase (before MFMA): the post-MFMA barrier is removed so waves de-stagger by
// up to one phase -- wave A's MFMA cluster overlaps wave B's ds_read window (LDS pipe || MFMA
// pipe). Hazard audit: MFMA is register-only; in-iteration reads (cur buf) and stages (next buf)
// are disjoint; every RAW keeps its adjacent {counted vmcnt -> s_barrier} pair; cross-iteration
// WAR pairs remain >=4 barriers apart. Ledger: P0 wait v4 (B-hi landed), P1 wait v4 (A-hi),
// P2 no wait, P3 wait v4 (A-lo,B-lo of t+1). Tail (pf=false) drains v0 at P0.
// EPI==0: bf16 gelu(acc*sc+bi); EPI==1: f32 acc*sc+bi. Output row-stride hardcoded 4096.
template<int EPI>
__global__ __launch_bounds__(512, 2)
void gemm8p(const unsigned short* __restrict__ A, const unsigned short* __restrict__ B,
            const float* __restrict__ scale, const float* __restrict__ bias,
            void* __restrict__ Cout, int K) {
    extern __shared__ __align__(16) char sm[];   // 131072 bytes dynamic

    const int tid  = threadIdx.x;
    const int lane = tid & 63;
    const int wid  = tid >> 6;
    const int wm   = wid >> 2, wn = wid & 3;
    const int widb = wid << 10;

    // T1: bijective XCD swizzle (m204)
    const int nwg  = gridDim.x;
    const int q    = nwg >> 3, r = nwg & 7;
    const int xcd  = blockIdx.x & 7, bidx = blockIdx.x >> 3;
    const int swz  = xcd * q + (xcd < r ? xcd : r) + bidx;
    const int tm   = swz / NTN, tn = swz % NTN;

    const size_t rowbytes = (size_t)K * 2;
    const char* Ag = (const char*)A + (size_t)tm * 256 * rowbytes;
    const char* Bg = (const char*)B + (size_t)tn * 256 * rowbytes;

    const int l16   = lane & 15;
    const int colk0 = (((lane >> 4) ^ (lane & 7)) << 4);       // swizzled col for kk=0
    const int colk1 = (((4 | (lane >> 4)) ^ (lane & 7)) << 4); // swizzled col for kk=1

    f32x4  acc[8][4] = {};
    bf16x8 af[4][2], bl[2][2], bh[2][2];

    const int NT = K >> 6;

// stage one 16KB quarter (PART: 0=rows 0-127, 1=rows 128-255) of a 256x64bf16 tile.
// LDS dest linear (wave-uniform base + lane*16); global source pre-inverse-swizzled (rule 21).
#define STAGE(GB, LB, PART, KTB) { \
    _Pragma("unroll") \
    for (int l_ = 0; l_ < 2; ++l_) { \
        const int po_   = ((PART) << 14) + (l_ << 13) + widb + (lane << 4); \
        const int prow_ = po_ >> 7; \
        const int lcb_  = (po_ & 127) ^ ((prow_ & 7) << 4); \
        __builtin_amdgcn_global_load_lds( \
            (gchar*)((GB) + (size_t)prow_ * rowbytes + (KTB) + (size_t)lcb_), \
            (lchar*)((LB) + po_), 16, 0, 0); \
    } }

#define SFENCE __builtin_amdgcn_sched_barrier(0)
#define WAITV4 { SFENCE; asm volatile("s_waitcnt vmcnt(4)"); SFENCE; }
#define WAITV0 { SFENCE; asm volatile("s_waitcnt vmcnt(0)"); SFENCE; }
#define BARR   { SFENCE; __builtin_amdgcn_s_barrier(); SFENCE; }

    // prologue: tile 0 -> buffer 0; issue order matches consumption priority
    STAGE(Ag, sm,         0, (size_t)0);   // A-lo
    STAGE(Bg, sm + 32768, 0, (size_t)0);   // B-lo
    STAGE(Bg, sm + 32768, 1, (size_t)0);   // B-hi
    STAGE(Ag, sm,         1, (size_t)0);   // A-hi
    WAITV4; BARR;                          // A-lo,B-lo landed; B-hi,A-hi may fly

    for (int t = 0; t < NT; ++t) {
        char* Al = sm + ((t & 1) << 16);
        char* Bl = Al + 32768;
        char* An = sm + (((t & 1) ^ 1) << 16);
        char* Bn = An + 32768;
        const bool   pf  = (t + 1 < NT);
        const size_t ktb = ((size_t)(t + 1)) << 7;  // (t+1)*64 bf16 = *128 bytes

        // ---- phase 0: read A-lo + B-lo frags; stage A-lo(t+1) ----
        {
            const int ab = (wm << 6) + l16;
            #pragma unroll
            for (int mm = 0; mm < 4; ++mm) {
                const int ro = (ab + mm * 16) * 128;
                af[mm][0] = *(const bf16x8*)(Al + ro + colk0);
                af[mm][1] = *(const bf16x8*)(Al + ro + colk1);
            }
            const int bb = (wn << 5) + l16;
            #pragma unroll
            for (int nn = 0; nn < 2; ++nn) {
                const int ro = (bb + nn * 16) * 128;
                bl[nn][0] = *(const bf16x8*)(Bl + ro + colk0);
                bl[nn][1] = *(const bf16x8*)(Bl + ro + colk1);
            }
            if (pf) { STAGE(Ag, An, 0, ktb); WAITV4; }
            else    { WAITV0; }           // tail: nothing staged, counted wait would no-op -> drain
            BARR;                          // guarantees B-hi(t) for phase 1
            __builtin_amdgcn_s_setprio(1);
            #pragma unroll
            for (int mm = 0; mm < 4; ++mm)
                #pragma unroll
                for (int nn = 0; nn < 2; ++nn) {
                    acc[mm][nn] = MFMA16(af[mm][0], bl[nn][0], acc[mm][nn]);
                    acc[mm][nn] = MFMA16(af[mm][1], bl[nn][1], acc[mm][nn]);
                }
            __builtin_amdgcn_s_setprio(0);
            SFENCE;                        // no barrier: next phase's reads may overlap others' MFMA
        }
        // ---- phase 1: read B-hi frags; stage B-lo(t+1) ----
        {
            const int bb = 128 + (wn << 5) + l16;
            #pragma unroll
            for (int nn = 0; nn < 2; ++nn) {
                const int ro = (bb + nn * 16) * 128;
                bh[nn][0] = *(const bf16x8*)(Bl + ro + colk0);
                bh[nn][1] = *(const bf16x8*)(Bl + ro + colk1);
            }
            if (pf) { STAGE(Bg, Bn, 0, ktb); WAITV4; }  // tail: all landed, no wait
            BARR;                          // guarantees A-hi(t) for phase 2
            __builtin_amdgcn_s_setprio(1);
            #pragma unroll
            for (int mm = 0; mm < 4; ++mm)
                #pragma unroll
                for (int nn = 0; nn < 2; ++nn) {
                    acc[mm][2 + nn] = MFMA16(af[mm][0], bh[nn][0], acc[mm][2 + nn]);
                    acc[mm][2 + nn] = MFMA16(af[mm][1], bh[nn][1], acc[mm][2 + nn]);
                }
            __builtin_amdgcn_s_setprio(0);
            SFENCE;
        }
        // ---- phase 2: read A-hi frags; stage B-hi(t+1) ----
        {
            const int ab = 128 + (wm << 6) + l16;
            #pragma unroll
            for (int mm = 0; mm < 4; ++mm) {
                const int ro = (ab + mm * 16) * 128;
                af[mm][0] = *(const bf16x8*)(Al + ro + colk0);
                af[mm][1] = *(const bf16x8*)(Al + ro + colk1);
            }
            if (pf) STAGE(Bg, Bn, 1, ktb);
            BARR;                          // phase 3 reads nothing new: no vmcnt
            __builtin_amdgcn_s_setprio(1);
            #pragma unroll
            for (int mm = 0; mm < 4; ++mm)
                #pragma unroll
                for (int nn = 0; nn < 2; ++nn) {
                    acc[4 + mm][nn] = MFMA16(af[mm][0], bl[nn][0], acc[4 + mm][nn]);
                    acc[4 + mm][nn] = MFMA16(af[mm][1], bl[nn][1], acc[4 + mm][nn]);
                }
            __builtin_amdgcn_s_setprio(0);
            SFENCE;
        }
        // ---- phase 3: stage A-hi(t+1) ----
        {
            if (pf) { STAGE(Ag, An, 1, ktb); WAITV4; }  // guarantees A-lo,B-lo(t+1) for next phase 0
            BARR;
            __builtin_amdgcn_s_setprio(1);
            #pragma unroll
            for (int mm = 0; mm < 4; ++mm)
                #pragma unroll
                for (int nn = 0; nn < 2; ++nn) {
                    acc[4 + mm][2 + nn] = MFMA16(af[mm][0], bh[nn][0], acc[4 + mm][2 + nn]);
                    acc[4 + mm][2 + nn] = MFMA16(af[mm][1], bh[nn][1], acc[4 + mm][2 + nn]);
                }
            __builtin_amdgcn_s_setprio(0);
            SFENCE;
        }
    }
#undef STAGE
#undef SFENCE
#undef WAITV4
#undef WAITV0
#undef BARR

    // epilogue: C/D frag layout col=lane&15, row=(lane>>4)*4+r  [m89/m91]
    const int rg = (lane >> 4) << 2;
    #pragma unroll
    for (int j = 0; j < 4; ++j) {
        const int col = tn * 256 + ((j >> 1) << 7) + (wn << 5) + ((j & 1) << 4) + l16;
        const float sc = scale[col];
        const float bi = bias[col];
        #pragma unroll
        for (int m = 0; m < 8; ++m) {
            const int row0 = tm * 256 + ((m >> 2) << 7) + (wm << 6) + ((m & 3) << 4) + rg;
            #pragma unroll
            for (int rr = 0; rr < 4; ++rr) {
                float v = acc[m][j][rr] * sc + bi;
                if (EPI == 0) {
                    float g = 0.5f * v * (1.0f + erff(v * 0.70710678118654752f));
                    ((unsigned short*)Cout)[(size_t)(row0 + rr) * 4096 + col] = f2bf(g);
                } else {
                    ((float*)Cout)[(size_t)(row0 + rr) * 4096 + col] = v;
                }
            }
        }
    }
}

extern "C" void kernel_launch(void* const* d_in, const int* in_sizes, int n_in,
                              void* d_out, int out_size, void* d_ws, size_t ws_size,
                              hipStream_t stream) {
    const float* x   = (const float*)d_in[0];
    const int*   w1q = (const int*)d_in[1];
    const float* s1  = (const float*)d_in[2];
    const float* b1  = (const float*)d_in[3];
    const int*   w2q = (const int*)d_in[4];
    const float* s2  = (const float*)d_in[5];
    const float* b2  = (const float*)d_in[6];
    float*       out = (float*)d_out;

    // allow 128 KiB dynamic LDS (idempotent, not a stream op)
    hipFuncSetAttribute((const void*)gemm8p<0>, hipFuncAttributeMaxDynamicSharedMemorySize, 131072);
    hipFuncSetAttribute((const void*)gemm8p<1>, hipFuncAttributeMaxDynamicSharedMemorySize, 131072);

    char* ws = (char*)d_ws;
    const size_t XBF  = (size_t)NROWS   * IN_DIM  * 2;
    const size_t W1BF = (size_t)HID_DIM * IN_DIM  * 2;
    const size_t W2BF = (size_t)OUT_DIM * HID_DIM * 2;
    const size_t FIXED = XBF + W1BF + W2BF;

    unsigned short* xbf  = (unsigned short*)ws;
    unsigned short* w1bf = (unsigned short*)(ws + XBF);
    unsigned short* w2bf = (unsigned short*)(ws + XBF + W1BF);
    unsigned short* hbuf = (unsigned short*)(ws + FIXED);

    {
        int nvx = NROWS * IN_DIM / 8;
        cvt_f32_bf16_k<<<(nvx + 255) / 256, 256, 0, stream>>>((const float4*)x, (uint4*)xbf, nvx);
        int nv1 = HID_DIM * IN_DIM / 8;
        cvt_i32_bf16_k<<<(nv1 + 255) / 256, 256, 0, stream>>>((const int4*)w1q, (uint4*)w1bf, nv1);
        int nv2 = OUT_DIM * HID_DIM / 8;
        cvt_i32_bf16_k<<<(nv2 + 255) / 256, 256, 0, stream>>>((const int4*)w2q, (uint4*)w2bf, nv2);
    }

    // chunk M (multiples of 256) so h fits in remaining workspace
    size_t avail = (ws_size > FIXED) ? (ws_size - FIXED) : 0;
    long rp = (long)(avail / ((size_t)HID_DIM * 2));
    rp = (rp / 256) * 256;
    if (rp > NROWS) rp = NROWS;
    if (rp < 256)   rp = 256;

    for (int r0 = 0; r0 < NROWS; r0 += (int)rp) {
        int rows = (int)(((long)(NROWS - r0) < rp) ? (NROWS - r0) : rp);
        dim3 g(NTN * (rows / 256));
        gemm8p<0><<<g, 512, 131072, stream>>>(xbf + (size_t)r0 * IN_DIM, w1bf, s1, b1,
                                              (void*)hbuf, IN_DIM);
        gemm8p<1><<<g, 512, 131072, stream>>>(hbuf, w2bf, s2, b2,
                                              (void*)(out + (size_t)r0 * OUT_DIM), HID_DIM);
    }
    (void)in_sizes; (void)n_in; (void)out_size;
}